// Round 13
// baseline (192.759 us; speedup 1.0000x reference)
//
#include <hip/hip_runtime.h>
#include <hip/hip_fp16.h>
#include <math.h>

#define Nn 10000
#define Ee 160000
#define NBb 8
#define Gg 100
#define NT 5
#define CSRMAX 230400            // >= Ee + 7*Nn, multiple of 256
#define EDGEBLK (CSRMAX / 256)   // 900
#define DEGBLK (Ee / 256)        // 625

typedef _Float16 half8v __attribute__((ext_vector_type(8)));
typedef float f32x4v __attribute__((ext_vector_type(4)));

// sh record per slot: [0..3]=sh0..3, [4..7]=sh4..7, [8]=sh8, [9]=src bits,
// [10]=sender-type bits, [11]=0
// SESSION LEDGER (hard-won, do not regress):
//  - 48B f32 record: keep (r8 f16-shrink regressed).
//  - NO atomicAdd into d_out (+66us, r8/r9). NO per-wave __threadfence or
//    done-counter epilogues (r11: 231us k_node1). NO cooperative fusion
//    (r7: 10x slower). Keep g_nodeE + separate k_energy with plain stores.
//  - Node kernels: 1-wave-per-node, 4 nodes/block (r4 4-wave/node regressed).
//  - Self-clean invariants (r11/r12-verified): k_edge restores g_er=-1;
//    k_node1 resets g_deg/g_cursor; k_first (once) establishes; k_deg
//    merged into k_init blocks 17+ (r12: -4us).
//  - THIS ROUND: depth-2 software pipeline across node batches (two NAMED
//    register sets, wave-uniform branches) — r3's bundled attempt isolated.
__device__ __align__(16) float g_shc[(size_t)CSRMAX * 12];
// R in fp16, slot-pair interleaved: g_R2[pair*64 + chan] = (R[2p][c], R[2p+1][c])
__device__ __align__(16) __half2 g_R2[(size_t)(CSRMAX / 2) * 64];
__device__ float g_h1b[Nn * 64];   // layer-1 h'@Wup1
__device__ float g_hscb[Nn * 64];  // layer-1 h'@Wsc1
__device__ float g_nodeE[2][Nn];   // per-layer node energies (no atomics)
__device__ int   g_deg[Nn];
__device__ int   g_offs[Nn + 1];
__device__ int   g_cursor[Nn];
__device__ int2  g_er[CSRMAX];     // per-slot (sender, receiver); .x=-1 for pads
// precomputed algebra (k_init)
__device__ float g_W1T[64 * NBb];  // W_r1 transposed: [j][k]
__device__ float g_E1[NT * 64];    // Wembed@Wup0  (layer-0 h1 rows, L1-resident)
__device__ float g_Esc[NT * 64];   // Wembed@Wsc0 (scratch)
__device__ float g_T1[NT * 64];    // Esc@Wup1
__device__ float g_T2[NT * 64];    // Esc@Wsc1
__device__ float g_M12[64 * 128];  // [k][0:64]=Wp0@Wup1 row, [k][64:128]=Wp0@Wsc1 row
__device__ float g_wp0ro[64];      // Wp0@wro0
__device__ float g_wpro[64];       // Wp1@wro1
__device__ float g_t0[NT];         // Esc@wro0

// One-time invariant establishment (static-flag guarded on host; idempotent
// and first-in-sequence, so inclusion in a captured graph is also correct).
__global__ __launch_bounds__(256) void k_first(float* __restrict__ out, int out_size) {
    int i = blockIdx.x * 256 + threadIdx.x;
    if (i < CSRMAX) g_er[i] = make_int2(-1, -1);
    if (i < Nn) { g_deg[i] = 0; g_cursor[i] = 0; }
    if (i < out_size) out[i] = 0.0f;
}

// Merged [r12-verified]: blocks 0-16 precompute algebra tables; blocks 17..
// count degrees (disjoint state; g_deg==0 by self-clean invariant).
__global__ __launch_bounds__(256) void k_init(const float* __restrict__ Wr1,
                                              const float* __restrict__ Wembed,
                                              const float* __restrict__ Wup,
                                              const float* __restrict__ Wsc,
                                              const float* __restrict__ Wprod,
                                              const float* __restrict__ wro,
                                              const int* __restrict__ eidx) {
    int t = threadIdx.x;
    int b = blockIdx.x;
    if (b >= 17) {
        int e = (b - 17) * 256 + t;
        if (e < Ee) atomicAdd(&g_deg[eidx[Ee + e]], 1);
        return;
    }
    if (b == 0) {
        for (int i = t; i < 64 * NBb; i += 256) {
            int k = i >> 6, j = i & 63;  // Wr1[k][j]
            g_W1T[j * NBb + k] = Wr1[i];
        }
        for (int i = t; i < NT * 64; i += 256) {
            int g = i >> 6, c = i & 63;
            float s1 = 0.f, s2 = 0.f;
            for (int j = 0; j < 64; j++) {
                float w = Wembed[g * 64 + j];
                s1 += w * Wup[j * 64 + c];
                s2 += w * Wsc[j * 64 + c];
            }
            g_E1[i] = s1; g_Esc[i] = s2;
        }
        if (t < 64) {
            float s1 = 0.f, s2 = 0.f;
            for (int c = 0; c < 64; c++) {
                s1 += Wprod[t * 64 + c] * wro[c];
                s2 += Wprod[4096 + t * 64 + c] * wro[64 + c];
            }
            g_wp0ro[t] = s1; g_wpro[t] = s2;
        }
        __syncthreads();
        for (int i = t; i < NT * 64; i += 256) {
            int g = i >> 6, c = i & 63;
            float s1 = 0.f, s2 = 0.f;
            for (int j = 0; j < 64; j++) {
                float w = g_Esc[g * 64 + j];
                s1 += w * Wup[4096 + j * 64 + c];
                s2 += w * Wsc[4096 + j * 64 + c];
            }
            g_T1[i] = s1; g_T2[i] = s2;
        }
        if (t < NT) {
            float s = 0.f;
            for (int j = 0; j < 64; j++) s += g_Esc[t * 64 + j] * wro[j];
            g_t0[t] = s;
        }
    } else {
        int idx = (b - 1) * 256 + t;          // 0..4095
        int k = idx >> 6, c = idx & 63;
        float s1 = 0.f, s2 = 0.f;
        for (int j = 0; j < 64; j++) {
            float w = Wprod[k * 64 + j];       // wave-uniform -> scalar
            s1 += w * Wup[4096 + j * 64 + c];
            s2 += w * Wsc[4096 + j * 64 + c];
        }
        g_M12[k * 128 + c] = s1;
        g_M12[k * 128 + 64 + c] = s2;
    }
}

// prefix sum of degrees padded up to multiples of 8
__global__ __launch_bounds__(1024) void k_scan() {
    __shared__ int part[1024];
    int t = threadIdx.x;
    const int CH = (Nn + 1023) / 1024;  // 10
    int st = t * CH;
    int en = st + CH; if (en > Nn) en = Nn;
    int s = 0;
    for (int i = st; i < en; i++) s += (g_deg[i] + 7) & ~7;
    part[t] = s;
    __syncthreads();
    for (int d = 1; d < 1024; d <<= 1) {
        int v = (t >= d) ? part[t - d] : 0;
        __syncthreads();
        part[t] += v;
        __syncthreads();
    }
    int base = (t == 0) ? 0 : part[t - 1];
    for (int i = st; i < en; i++) { g_offs[i] = base; base += (g_deg[i] + 7) & ~7; }
    if (t == 1023) g_offs[Nn] = part[1023];
}

__global__ __launch_bounds__(256) void k_fill(const int* __restrict__ eidx) {
    int e = blockIdx.x * 256 + threadIdx.x;
    if (e >= Ee) return;
    int snd = eidx[e];
    int r = eidx[Ee + e];
    int p = g_offs[r] + atomicAdd(&g_cursor[r], 1);
    g_er[p] = make_int2(snd, r);
}

// Edge MLP [r5 proven + r11-verified self-clean]. One thread per slot computes
// layer-1 activations (K=8, VALU), stages them f16 into a granule-XOR-swizzled
// LDS A-tile; the 64x64 W2 matmul runs on the matrix pipe
// (mfma_f32_16x16x32_f16). Sender type stashed in record slot 10.
__global__ __launch_bounds__(256) void k_edge(const float* __restrict__ pos,
                                              const float* __restrict__ br1,
                                              const float* __restrict__ Wr2,
                                              const int* __restrict__ atom_types) {
    int t = threadIdx.x;
    __shared__ _Float16 sA[256 * 64];  // 32 KB: activations, row=slot, XOR-swizzled 8-half granules
    __shared__ _Float16 sB[64 * 64];   // 8 KB: W2 transposed, sB[c][j] = Wr2[j][c]
    int total = g_offs[Nn];
    if (blockIdx.x * 256 >= total) return;

    // stage W2^T as f16 (coalesced global read, one-time LDS write)
    for (int i = t; i < 64 * 64; i += 256)
        sB[(i & 63) * 64 + (i >> 6)] = (_Float16)Wr2[i];

    int s = blockIdx.x * 256 + t;
    int2 er = g_er[s];
    g_er[s] = make_int2(-1, -1);   // self-clean: pad invariant for next iter
    bool real = (er.x >= 0);
    int snd = real ? er.x : 0;
    int rcv = real ? er.y : 0;
    int stype = atom_types[snd];   // gathered 4B; issued early with pos loads

    float vx = pos[3 * rcv + 0] - pos[3 * snd + 0];
    float vy = pos[3 * rcv + 1] - pos[3 * snd + 1];
    float vz = pos[3 * rcv + 2] - pos[3 * snd + 2];
    float r = sqrtf(vx * vx + vy * vy + vz * vz);
    float inv = __builtin_amdgcn_rcpf(fmaxf(r, 1e-9f));
    float x = vx * inv, y = vy * inv, z = vz * inv;
    const float s3 = 1.7320508f;
    {
        float4* shp = (float4*)(g_shc + (size_t)s * 12);
        if (real) {
            shp[0] = make_float4(1.0f, x, y, z);
            shp[1] = make_float4(s3 * x * y, s3 * y * z, 0.5f * (3.0f * z * z - 1.0f), s3 * x * z);
            shp[2] = make_float4(0.5f * s3 * (x * x - y * y), __int_as_float(snd),
                                 __int_as_float(stype), 0.f);
        } else {
            shp[0] = make_float4(0.f, 0.f, 0.f, 0.f);
            shp[1] = make_float4(0.f, 0.f, 0.f, 0.f);
            shp[2] = make_float4(0.f, 0.f, 0.f, 0.f);
        }
    }

    float xx = r * 0.2f;
    float env = 0.0f;
    if (xx < 1.0f) {
        float x2 = xx * xx;
        float x6 = x2 * x2 * x2;
        float x7 = x6 * xx;
        float x8 = x7 * xx;
        env = 1.0f - 28.0f * x6 + 48.0f * x7 - 21.0f * x8;
    }
    const float pref = 0.63245553f;  // sqrt(2/R_MAX)
    const float PI_F = 3.14159265358979f;
    float fac = pref * inv * env;
    float ef[NBb];
#pragma unroll
    for (int k = 0; k < NBb; k++)
        ef[k] = fac * __sinf((float)(k + 1) * PI_F * r * 0.2f);

    // layer 1 (K=8) + silu per lane; f16-pack 8 at a time into swizzled granules
#pragma unroll
    for (int gnl = 0; gnl < 8; gnl++) {
        half8v h8;
#pragma unroll
        for (int i2 = 0; i2 < 8; i2++) {
            int j = gnl * 8 + i2;
            float a = br1[j];
#pragma unroll
            for (int k = 0; k < NBb; k++) a += ef[k] * g_W1T[j * NBb + k];
            a = a * __builtin_amdgcn_rcpf(1.0f + __expf(-a));
            h8[i2] = (_Float16)(real ? a : 0.0f);
        }
        int pg = gnl ^ (t & 7);   // granule XOR swizzle -> conflict-free b128 r/w
        *(half8v*)&sA[t * 64 + pg * 8] = h8;
    }
    __syncthreads();

    int lane = t & 63;
    int w = t >> 6;
    // B fragments: lane holds B[k = (lane>>4)*8 + i][col = lane&15] -> contiguous
    // 8 halfs of sB row (n*16 + lane&15), k-halves kk=0/1. 32 VGPRs, loaded once.
    half8v Bf[4][2];
#pragma unroll
    for (int n = 0; n < 4; n++) {
#pragma unroll
        for (int kk = 0; kk < 2; kk++) {
            int c = n * 16 + (lane & 15);
            int j0 = kk * 32 + (lane >> 4) * 8;
            Bf[n][kk] = *(const half8v*)&sB[c * 64 + j0];
        }
    }
    // each wave MFMAs its own 64 staged edges (rows w*64 .. w*64+63)
#pragma unroll
    for (int m = 0; m < 4; m++) {
        int row = w * 64 + m * 16 + (lane & 15);
        int q0 = (lane >> 4) ^ (lane & 7);
        int q1 = (4 + (lane >> 4)) ^ (lane & 7);
        half8v A0 = *(const half8v*)&sA[row * 64 + q0 * 8];
        half8v A1 = *(const half8v*)&sA[row * 64 + q1 * 8];
        size_t pairbase = (size_t)blockIdx.x * 128 + (size_t)w * 32 + m * 8 + (lane >> 4) * 2;
        int cbase = lane & 15;
#pragma unroll
        for (int n = 0; n < 4; n++) {
            f32x4v d = {0.f, 0.f, 0.f, 0.f};
            d = __builtin_amdgcn_mfma_f32_16x16x32_f16(A0, Bf[n][0], d, 0, 0, 0);
            d = __builtin_amdgcn_mfma_f32_16x16x32_f16(A1, Bf[n][1], d, 0, 0, 0);
            int c = n * 16 + cbase;
            // D rows (lane>>4)*4+{0..3} = slots pairbase*2..+3 -> two half2 pairs
            g_R2[pairbase * 64 + c]       = __floats2half2_rn(d[0], d[1]);
            g_R2[(pairbase + 1) * 64 + c] = __floats2half2_rn(d[2], d[3]);
        }
    }
}

// ---- depth-2 pipelined node batch pieces (named register sets, rule-#20) ----
// LOAD: issue the latency-bound loads for a batch (R2 line + meta + gather).
#define NB_LOAD_E1(j0, r2t, hv)                                                  \
    {                                                                            \
        const float* __restrict__ rp = g_shc + (size_t)(j0) * 12;                \
        _Pragma("unroll")                                                        \
        for (int kk = 0; kk < 4; kk++)                                           \
            r2t[kk] = g_R2[((j0) / 2 + kk) * 64 + lane];                         \
        int stv[8];                                                              \
        _Pragma("unroll")                                                        \
        for (int k = 0; k < 8; k++) stv[k] = __float_as_int(rp[k * 12 + 10]);    \
        _Pragma("unroll")                                                        \
        for (int k = 0; k < 8; k++) hv[k] = g_E1[stv[k] * 64 + lane];            \
    }

#define NB_LOAD_H(j0, r2t, hv)                                                   \
    {                                                                            \
        const float* __restrict__ rp = g_shc + (size_t)(j0) * 12;                \
        _Pragma("unroll")                                                        \
        for (int kk = 0; kk < 4; kk++)                                           \
            r2t[kk] = g_R2[((j0) / 2 + kk) * 64 + lane];                         \
        int srcv[8];                                                             \
        _Pragma("unroll")                                                        \
        for (int k = 0; k < 8; k++) srcv[k] = __float_as_int(rp[k * 12 + 9]);    \
        _Pragma("unroll")                                                        \
        for (int k = 0; k < 8; k++)                                              \
            hv[k] = g_h1b[(size_t)srcv[k] * 64 + lane];                          \
    }

// FMA: consume a batch; record re-reads are L1-hot (line fetched in LOAD).
#define NB_FMA(j0, r2t, hv)                                                      \
    {                                                                            \
        const float* __restrict__ rp = g_shc + (size_t)(j0) * 12;                \
        _Pragma("unroll")                                                        \
        for (int k = 0; k < 8; k++) {                                            \
            float4 ra = *(const float4*)(rp + k * 12);                           \
            float4 rb = *(const float4*)(rp + k * 12 + 4);                       \
            float s8 = rp[k * 12 + 8];                                           \
            float rv = (k & 1) ? __high2float((r2t)[k >> 1]) : __low2float((r2t)[k >> 1]); \
            float tv = rv * (hv)[k];                                             \
            A[0] += ra.x * tv; A[1] += ra.y * tv; A[2] += ra.z * tv;             \
            A[3] += ra.w * tv; A[4] += rb.x * tv; A[5] += rb.y * tv;             \
            A[6] += rb.z * tv; A[7] += rb.w * tv; A[8] += s8 * tv;               \
        }                                                                        \
    }

// Main-path pipeline (nb<=4 common case): LOAD(b+1) issued before FMA(b);
// two named sets a/b alternate; all branches wave-uniform (nb is scalar).
#define NODE_PIPELINE(LOADM)                                                     \
    __half2 r2a[4], r2b[4];                                                      \
    float hva[8], hvb[8];                                                        \
    size_t j0 = (size_t)boff;                                                    \
    if (nb >= 1) LOADM(j0, r2a, hva);                                            \
    if (nb >= 2) LOADM(j0 + 8, r2b, hvb);                                        \
    if (nb >= 1) NB_FMA(j0, r2a, hva);                                           \
    if (nb >= 3) LOADM(j0 + 16, r2a, hva);                                       \
    if (nb >= 2) NB_FMA(j0 + 8, r2b, hvb);                                       \
    if (nb >= 4) LOADM(j0 + 24, r2b, hvb);                                       \
    if (nb >= 3) NB_FMA(j0 + 16, r2a, hva);                                      \
    if (nb >= 4) NB_FMA(j0 + 24, r2b, hvb);                                      \
    for (int b = 4; b < nb; b++) {                                               \
        size_t jt = j0 + (size_t)b * 8;                                          \
        LOADM(jt, r2a, hva);                                                     \
        NB_FMA(jt, r2a, hva);                                                    \
    }

// Layer-0 node kernel: 4 nodes/block, 1 wave/node, depth-2 pipelined batches.
__global__ __launch_bounds__(256) void k_node0(const int* __restrict__ atom_types) {
    int t = threadIdx.x;
    int node = blockIdx.x * 4 + (t >> 6);
    int lane = t & 63;
    int boff = __builtin_amdgcn_readfirstlane(g_offs[node]);
    int nb = (__builtin_amdgcn_readfirstlane(g_deg[node]) + 7) >> 3;
    float A[9];
#pragma unroll
    for (int m = 0; m < 9; m++) A[m] = 0.0f;
    NODE_PIPELINE(NB_LOAD_E1)
    const float invn = 1.0f / 16.0f;  // AVG_NEI
    float q = A[0] * invn;
#pragma unroll
    for (int m = 0; m < 9; m++) {
        float a = A[m] * invn;
        q += a * a;
    }
    int type = __builtin_amdgcn_readfirstlane(atom_types[node]);
    float h1n = g_T1[type * 64 + lane];
    float hscn = g_T2[type * 64 + lane];
#pragma unroll
    for (int k = 0; k < 64; k++) {
        float qk = __shfl(q, k, 64);
        h1n += qk * g_M12[k * 128 + lane];
        hscn += qk * g_M12[k * 128 + 64 + lane];
    }
    g_h1b[node * 64 + lane] = h1n;
    g_hscb[node * 64 + lane] = hscn;
    float v = q * g_wp0ro[lane];
#pragma unroll
    for (int off = 32; off > 0; off >>= 1) v += __shfl_down(v, off, 64);
    if (lane == 0) g_nodeE[0][node] = v + g_t0[type];
}

// Layer-1: node_e = q.(Wp1@wro1) + hscb.wro1 — depth-2 pipelined batches.
// Self-cleans g_deg/g_cursor (2 plain stores; NO fence, NO counter — r11).
__global__ __launch_bounds__(256) void k_node1(const float* __restrict__ wro) {
    int t = threadIdx.x;
    int node = blockIdx.x * 4 + (t >> 6);
    int lane = t & 63;
    int boff = __builtin_amdgcn_readfirstlane(g_offs[node]);
    int nb = (__builtin_amdgcn_readfirstlane(g_deg[node]) + 7) >> 3;
    float A[9];
#pragma unroll
    for (int m = 0; m < 9; m++) A[m] = 0.0f;
    NODE_PIPELINE(NB_LOAD_H)
    const float invn = 1.0f / 16.0f;  // AVG_NEI
    float q = A[0] * invn;
#pragma unroll
    for (int m = 0; m < 9; m++) {
        float a = A[m] * invn;
        q += a * a;
    }
    float v = q * g_wpro[lane] + g_hscb[node * 64 + lane] * wro[lane];
#pragma unroll
    for (int off = 32; off > 0; off >>= 1) v += __shfl_down(v, off, 64);
    if (lane == 0) {
        g_nodeE[1][node] = v;
        g_deg[node] = 0;      // self-clean for next iteration's k_init
        g_cursor[node] = 0;
    }
}

// One wave per graph; batch is sorted -> binary-search the node range,
// coalesced reduce, single plain store. Zero atomics (r8/r9: atomics on the
// output buffer cost +66us — never atomic into d_out).
__global__ __launch_bounds__(64) void k_energy(const int* __restrict__ batch,
                                               float* __restrict__ out) {
    int g = blockIdx.x;
    int lane = threadIdx.x;
    int a = 0, b = Nn;
    while (a < b) { int m = (a + b) >> 1; if (batch[m] < g) a = m + 1; else b = m; }
    int st = a;
    b = Nn;
    while (a < b) { int m = (a + b) >> 1; if (batch[m] < g + 1) a = m + 1; else b = m; }
    int en = a;
    float s = 0.0f;
    for (int i = st + lane; i < en; i += 64) s += g_nodeE[0][i] + g_nodeE[1][i];
#pragma unroll
    for (int off = 32; off > 0; off >>= 1) s += __shfl_down(s, off, 64);
    if (lane == 0) out[g] = s;
}

static bool g_first_done = false;

extern "C" void kernel_launch(void* const* d_in, const int* in_sizes, int n_in,
                              void* d_out, int out_size, void* d_ws, size_t ws_size,
                              hipStream_t stream) {
    const float* pos     = (const float*)d_in[0];
    const float* W_embed = (const float*)d_in[1];
    const float* W_r1    = (const float*)d_in[2];
    const float* b_r1    = (const float*)d_in[3];
    const float* W_r2    = (const float*)d_in[4];
    const float* W_up    = (const float*)d_in[5];
    const float* W_sc    = (const float*)d_in[6];
    const float* W_prod  = (const float*)d_in[7];
    const float* w_ro    = (const float*)d_in[8];
    const int* atom_types = (const int*)d_in[9];
    const int* eidx       = (const int*)d_in[10];
    const int* batch      = (const int*)d_in[11];
    float* out = (float*)d_out;

    if (!g_first_done) {
        k_first<<<EDGEBLK, 256, 0, stream>>>(out, out_size);
        g_first_done = true;
    }
    k_init<<<17 + DEGBLK, 256, 0, stream>>>(W_r1, W_embed, W_up, W_sc, W_prod,
                                            w_ro, eidx);
    k_scan<<<1, 1024, 0, stream>>>();
    k_fill<<<DEGBLK, 256, 0, stream>>>(eidx);
    k_edge<<<EDGEBLK, 256, 0, stream>>>(pos, b_r1, W_r2, atom_types);
    k_node0<<<Nn / 4, 256, 0, stream>>>(atom_types);
    k_node1<<<Nn / 4, 256, 0, stream>>>(w_ro + 64);
    k_energy<<<Gg, 64, 0, stream>>>(batch, out);
}

// Round 14
// 181.958 us; speedup vs baseline: 1.0594x; 1.0594x over previous
//
#include <hip/hip_runtime.h>
#include <hip/hip_fp16.h>
#include <math.h>

#define Nn 10000
#define Ee 160000
#define NBb 8
#define Gg 100
#define NT 5
#define CSRMAX 230400            // >= Ee + 7*Nn, multiple of 256
#define EDGEBLK (CSRMAX / 256)   // 900
#define DEGBLK (Ee / 256)        // 625

typedef _Float16 half8v __attribute__((ext_vector_type(8)));
typedef float f32x4v __attribute__((ext_vector_type(4)));

// sh record per slot: [0..3]=sh0..3, [4..7]=sh4..7, [8]=sh8, [9]=src bits,
// [10]=sender-type bits, [11]=0
// SESSION LEDGER (hard-won, do not regress):
//  - 48B f32 record: keep (r8 f16-shrink regressed).
//  - NO atomicAdd into d_out (+66us, r8/r9). NO per-wave __threadfence or
//    done-counter epilogues (r11: 231us k_node1). NO cooperative fusion
//    (r7: 10x slower). Keep g_nodeE + separate k_energy with plain stores.
//  - Node kernels: 1-wave-per-node, 4 nodes/block, straight-line batches.
//    FOUR restructures falsified: r3 guarded-ILP, r4 4-wave/node, r13
//    depth-2 named-set pipeline (+9.5us). Compiler pins body at VGPR=32;
//    source-level pipelining does not materialize on this chip.
//  - Self-clean invariants (r11/r12-verified): k_edge restores g_er=-1;
//    k_node1 resets g_deg/g_cursor; k_first (once) establishes; k_deg
//    merged into k_init blocks 17+ (r12: -4us).
__device__ __align__(16) float g_shc[(size_t)CSRMAX * 12];
// R in fp16, slot-pair interleaved: g_R2[pair*64 + chan] = (R[2p][c], R[2p+1][c])
__device__ __align__(16) __half2 g_R2[(size_t)(CSRMAX / 2) * 64];
__device__ float g_h1b[Nn * 64];   // layer-1 h'@Wup1
__device__ float g_hscb[Nn * 64];  // layer-1 h'@Wsc1
__device__ float g_nodeE[2][Nn];   // per-layer node energies (no atomics)
__device__ int   g_deg[Nn];
__device__ int   g_offs[Nn + 1];
__device__ int   g_cursor[Nn];
__device__ int2  g_er[CSRMAX];     // per-slot (sender, receiver); .x=-1 for pads
// precomputed algebra (k_init)
__device__ float g_W1T[64 * NBb];  // W_r1 transposed: [j][k]
__device__ float g_E1[NT * 64];    // Wembed@Wup0  (layer-0 h1 rows, L1-resident)
__device__ float g_Esc[NT * 64];   // Wembed@Wsc0 (scratch)
__device__ float g_T1[NT * 64];    // Esc@Wup1
__device__ float g_T2[NT * 64];    // Esc@Wsc1
__device__ float g_M12[64 * 128];  // [k][0:64]=Wp0@Wup1 row, [k][64:128]=Wp0@Wsc1 row
__device__ float g_wp0ro[64];      // Wp0@wro0
__device__ float g_wpro[64];       // Wp1@wro1
__device__ float g_t0[NT];         // Esc@wro0

// One-time invariant establishment (static-flag guarded on host; idempotent
// and first-in-sequence, so inclusion in a captured graph is also correct).
__global__ __launch_bounds__(256) void k_first(float* __restrict__ out, int out_size) {
    int i = blockIdx.x * 256 + threadIdx.x;
    if (i < CSRMAX) g_er[i] = make_int2(-1, -1);
    if (i < Nn) { g_deg[i] = 0; g_cursor[i] = 0; }
    if (i < out_size) out[i] = 0.0f;
}

// Merged [r12-verified]: blocks 0-16 precompute algebra tables; blocks 17..
// count degrees (disjoint state; g_deg==0 by self-clean invariant).
__global__ __launch_bounds__(256) void k_init(const float* __restrict__ Wr1,
                                              const float* __restrict__ Wembed,
                                              const float* __restrict__ Wup,
                                              const float* __restrict__ Wsc,
                                              const float* __restrict__ Wprod,
                                              const float* __restrict__ wro,
                                              const int* __restrict__ eidx) {
    int t = threadIdx.x;
    int b = blockIdx.x;
    if (b >= 17) {
        int e = (b - 17) * 256 + t;
        if (e < Ee) atomicAdd(&g_deg[eidx[Ee + e]], 1);
        return;
    }
    if (b == 0) {
        for (int i = t; i < 64 * NBb; i += 256) {
            int k = i >> 6, j = i & 63;  // Wr1[k][j]
            g_W1T[j * NBb + k] = Wr1[i];
        }
        for (int i = t; i < NT * 64; i += 256) {
            int g = i >> 6, c = i & 63;
            float s1 = 0.f, s2 = 0.f;
            for (int j = 0; j < 64; j++) {
                float w = Wembed[g * 64 + j];
                s1 += w * Wup[j * 64 + c];
                s2 += w * Wsc[j * 64 + c];
            }
            g_E1[i] = s1; g_Esc[i] = s2;
        }
        if (t < 64) {
            float s1 = 0.f, s2 = 0.f;
            for (int c = 0; c < 64; c++) {
                s1 += Wprod[t * 64 + c] * wro[c];
                s2 += Wprod[4096 + t * 64 + c] * wro[64 + c];
            }
            g_wp0ro[t] = s1; g_wpro[t] = s2;
        }
        __syncthreads();
        for (int i = t; i < NT * 64; i += 256) {
            int g = i >> 6, c = i & 63;
            float s1 = 0.f, s2 = 0.f;
            for (int j = 0; j < 64; j++) {
                float w = g_Esc[g * 64 + j];
                s1 += w * Wup[4096 + j * 64 + c];
                s2 += w * Wsc[4096 + j * 64 + c];
            }
            g_T1[i] = s1; g_T2[i] = s2;
        }
        if (t < NT) {
            float s = 0.f;
            for (int j = 0; j < 64; j++) s += g_Esc[t * 64 + j] * wro[j];
            g_t0[t] = s;
        }
    } else {
        int idx = (b - 1) * 256 + t;          // 0..4095
        int k = idx >> 6, c = idx & 63;
        float s1 = 0.f, s2 = 0.f;
        for (int j = 0; j < 64; j++) {
            float w = Wprod[k * 64 + j];       // wave-uniform -> scalar
            s1 += w * Wup[4096 + j * 64 + c];
            s2 += w * Wsc[4096 + j * 64 + c];
        }
        g_M12[k * 128 + c] = s1;
        g_M12[k * 128 + 64 + c] = s2;
    }
}

// prefix sum of degrees padded up to multiples of 8
__global__ __launch_bounds__(1024) void k_scan() {
    __shared__ int part[1024];
    int t = threadIdx.x;
    const int CH = (Nn + 1023) / 1024;  // 10
    int st = t * CH;
    int en = st + CH; if (en > Nn) en = Nn;
    int s = 0;
    for (int i = st; i < en; i++) s += (g_deg[i] + 7) & ~7;
    part[t] = s;
    __syncthreads();
    for (int d = 1; d < 1024; d <<= 1) {
        int v = (t >= d) ? part[t - d] : 0;
        __syncthreads();
        part[t] += v;
        __syncthreads();
    }
    int base = (t == 0) ? 0 : part[t - 1];
    for (int i = st; i < en; i++) { g_offs[i] = base; base += (g_deg[i] + 7) & ~7; }
    if (t == 1023) g_offs[Nn] = part[1023];
}

__global__ __launch_bounds__(256) void k_fill(const int* __restrict__ eidx) {
    int e = blockIdx.x * 256 + threadIdx.x;
    if (e >= Ee) return;
    int snd = eidx[e];
    int r = eidx[Ee + e];
    int p = g_offs[r] + atomicAdd(&g_cursor[r], 1);
    g_er[p] = make_int2(snd, r);
}

// Edge MLP [r5 proven + r11-verified self-clean]. One thread per slot computes
// layer-1 activations (K=8, VALU), stages them f16 into a granule-XOR-swizzled
// LDS A-tile; the 64x64 W2 matmul runs on the matrix pipe
// (mfma_f32_16x16x32_f16). Sender type stashed in record slot 10.
__global__ __launch_bounds__(256) void k_edge(const float* __restrict__ pos,
                                              const float* __restrict__ br1,
                                              const float* __restrict__ Wr2,
                                              const int* __restrict__ atom_types) {
    int t = threadIdx.x;
    __shared__ _Float16 sA[256 * 64];  // 32 KB: activations, row=slot, XOR-swizzled 8-half granules
    __shared__ _Float16 sB[64 * 64];   // 8 KB: W2 transposed, sB[c][j] = Wr2[j][c]
    int total = g_offs[Nn];
    if (blockIdx.x * 256 >= total) return;

    // stage W2^T as f16 (coalesced global read, one-time LDS write)
    for (int i = t; i < 64 * 64; i += 256)
        sB[(i & 63) * 64 + (i >> 6)] = (_Float16)Wr2[i];

    int s = blockIdx.x * 256 + t;
    int2 er = g_er[s];
    g_er[s] = make_int2(-1, -1);   // self-clean: pad invariant for next iter
    bool real = (er.x >= 0);
    int snd = real ? er.x : 0;
    int rcv = real ? er.y : 0;
    int stype = atom_types[snd];   // gathered 4B; issued early with pos loads

    float vx = pos[3 * rcv + 0] - pos[3 * snd + 0];
    float vy = pos[3 * rcv + 1] - pos[3 * snd + 1];
    float vz = pos[3 * rcv + 2] - pos[3 * snd + 2];
    float r = sqrtf(vx * vx + vy * vy + vz * vz);
    float inv = __builtin_amdgcn_rcpf(fmaxf(r, 1e-9f));
    float x = vx * inv, y = vy * inv, z = vz * inv;
    const float s3 = 1.7320508f;
    {
        float4* shp = (float4*)(g_shc + (size_t)s * 12);
        if (real) {
            shp[0] = make_float4(1.0f, x, y, z);
            shp[1] = make_float4(s3 * x * y, s3 * y * z, 0.5f * (3.0f * z * z - 1.0f), s3 * x * z);
            shp[2] = make_float4(0.5f * s3 * (x * x - y * y), __int_as_float(snd),
                                 __int_as_float(stype), 0.f);
        } else {
            shp[0] = make_float4(0.f, 0.f, 0.f, 0.f);
            shp[1] = make_float4(0.f, 0.f, 0.f, 0.f);
            shp[2] = make_float4(0.f, 0.f, 0.f, 0.f);
        }
    }

    float xx = r * 0.2f;
    float env = 0.0f;
    if (xx < 1.0f) {
        float x2 = xx * xx;
        float x6 = x2 * x2 * x2;
        float x7 = x6 * xx;
        float x8 = x7 * xx;
        env = 1.0f - 28.0f * x6 + 48.0f * x7 - 21.0f * x8;
    }
    const float pref = 0.63245553f;  // sqrt(2/R_MAX)
    const float PI_F = 3.14159265358979f;
    float fac = pref * inv * env;
    float ef[NBb];
#pragma unroll
    for (int k = 0; k < NBb; k++)
        ef[k] = fac * __sinf((float)(k + 1) * PI_F * r * 0.2f);

    // layer 1 (K=8) + silu per lane; f16-pack 8 at a time into swizzled granules
#pragma unroll
    for (int gnl = 0; gnl < 8; gnl++) {
        half8v h8;
#pragma unroll
        for (int i2 = 0; i2 < 8; i2++) {
            int j = gnl * 8 + i2;
            float a = br1[j];
#pragma unroll
            for (int k = 0; k < NBb; k++) a += ef[k] * g_W1T[j * NBb + k];
            a = a * __builtin_amdgcn_rcpf(1.0f + __expf(-a));
            h8[i2] = (_Float16)(real ? a : 0.0f);
        }
        int pg = gnl ^ (t & 7);   // granule XOR swizzle -> conflict-free b128 r/w
        *(half8v*)&sA[t * 64 + pg * 8] = h8;
    }
    __syncthreads();

    int lane = t & 63;
    int w = t >> 6;
    // B fragments: lane holds B[k = (lane>>4)*8 + i][col = lane&15] -> contiguous
    // 8 halfs of sB row (n*16 + lane&15), k-halves kk=0/1. 32 VGPRs, loaded once.
    half8v Bf[4][2];
#pragma unroll
    for (int n = 0; n < 4; n++) {
#pragma unroll
        for (int kk = 0; kk < 2; kk++) {
            int c = n * 16 + (lane & 15);
            int j0 = kk * 32 + (lane >> 4) * 8;
            Bf[n][kk] = *(const half8v*)&sB[c * 64 + j0];
        }
    }
    // each wave MFMAs its own 64 staged edges (rows w*64 .. w*64+63)
#pragma unroll
    for (int m = 0; m < 4; m++) {
        int row = w * 64 + m * 16 + (lane & 15);
        int q0 = (lane >> 4) ^ (lane & 7);
        int q1 = (4 + (lane >> 4)) ^ (lane & 7);
        half8v A0 = *(const half8v*)&sA[row * 64 + q0 * 8];
        half8v A1 = *(const half8v*)&sA[row * 64 + q1 * 8];
        size_t pairbase = (size_t)blockIdx.x * 128 + (size_t)w * 32 + m * 8 + (lane >> 4) * 2;
        int cbase = lane & 15;
#pragma unroll
        for (int n = 0; n < 4; n++) {
            f32x4v d = {0.f, 0.f, 0.f, 0.f};
            d = __builtin_amdgcn_mfma_f32_16x16x32_f16(A0, Bf[n][0], d, 0, 0, 0);
            d = __builtin_amdgcn_mfma_f32_16x16x32_f16(A1, Bf[n][1], d, 0, 0, 0);
            int c = n * 16 + cbase;
            // D rows (lane>>4)*4+{0..3} = slots pairbase*2..+3 -> two half2 pairs
            g_R2[pairbase * 64 + c]       = __floats2half2_rn(d[0], d[1]);
            g_R2[(pairbase + 1) * 64 + c] = __floats2half2_rn(d[2], d[3]);
        }
    }
}

// Layer-0 batch: NO scattered gather — h1a row rebuilt from E1[stype] (1.25KB,
// L1-resident); stype rides in the record cache line (slot 10).
#define NODE_BATCH_E1(j0)                                                        \
    {                                                                            \
        const float* __restrict__ rp = g_shc + (size_t)(j0) * 12;                \
        __half2 r2t[4];                                                          \
        _Pragma("unroll")                                                        \
        for (int kk = 0; kk < 4; kk++)                                           \
            r2t[kk] = g_R2[((j0) / 2 + kk) * 64 + lane];                         \
        float s8v[8]; int stv[8];                                                \
        _Pragma("unroll")                                                        \
        for (int k = 0; k < 8; k++) {                                            \
            float4 rc = *(const float4*)(rp + k * 12 + 8);                       \
            s8v[k] = rc.x; stv[k] = __float_as_int(rc.z);                        \
        }                                                                        \
        float hv[8];                                                             \
        _Pragma("unroll")                                                        \
        for (int k = 0; k < 8; k++) hv[k] = g_E1[stv[k] * 64 + lane];            \
        _Pragma("unroll")                                                        \
        for (int k = 0; k < 8; k++) {                                            \
            float4 ra = *(const float4*)(rp + k * 12);                           \
            float4 rb = *(const float4*)(rp + k * 12 + 4);                       \
            float rv = (k & 1) ? __high2float(r2t[k >> 1]) : __low2float(r2t[k >> 1]); \
            float tv = rv * hv[k];                                               \
            A[0] += ra.x * tv; A[1] += ra.y * tv; A[2] += ra.z * tv;             \
            A[3] += ra.w * tv; A[4] += rb.x * tv; A[5] += rb.y * tv;             \
            A[6] += rb.z * tv; A[7] += rb.w * tv; A[8] += s8v[k] * tv;           \
        }                                                                        \
    }

// Layer-1 batch: genuine gather of h1b (data-dependent).
#define NODE_BATCH(j0)                                                           \
    {                                                                            \
        const float* __restrict__ rp = g_shc + (size_t)(j0) * 12;                \
        __half2 r2t[4];                                                          \
        _Pragma("unroll")                                                        \
        for (int kk = 0; kk < 4; kk++)                                           \
            r2t[kk] = g_R2[((j0) / 2 + kk) * 64 + lane];                         \
        float s8v[8]; int srcv[8];                                               \
        _Pragma("unroll")                                                        \
        for (int k = 0; k < 8; k++) {                                            \
            float2 rc = *(const float2*)(rp + k * 12 + 8);                       \
            s8v[k] = rc.x; srcv[k] = __float_as_int(rc.y);                       \
        }                                                                        \
        float hv[8];                                                             \
        _Pragma("unroll")                                                        \
        for (int k = 0; k < 8; k++)                                              \
            hv[k] = hsrc[(size_t)srcv[k] * 64 + lane];                           \
        _Pragma("unroll")                                                        \
        for (int k = 0; k < 8; k++) {                                            \
            float4 ra = *(const float4*)(rp + k * 12);                           \
            float4 rb = *(const float4*)(rp + k * 12 + 4);                       \
            float rv = (k & 1) ? __high2float(r2t[k >> 1]) : __low2float(r2t[k >> 1]); \
            float tv = rv * hv[k];                                               \
            A[0] += ra.x * tv; A[1] += ra.y * tv; A[2] += ra.z * tv;             \
            A[3] += ra.w * tv; A[4] += rb.x * tv; A[5] += rb.y * tv;             \
            A[6] += rb.z * tv; A[7] += rb.w * tv; A[8] += s8v[k] * tv;           \
        }                                                                        \
    }

// Layer-0 node kernel [r5/r12 verified]: 4 nodes/block, 1 wave/node.
__global__ __launch_bounds__(256) void k_node0(const int* __restrict__ atom_types) {
    int t = threadIdx.x;
    int node = blockIdx.x * 4 + (t >> 6);
    int lane = t & 63;
    int boff = __builtin_amdgcn_readfirstlane(g_offs[node]);
    int nb = (__builtin_amdgcn_readfirstlane(g_deg[node]) + 7) >> 3;
    float A[9];
#pragma unroll
    for (int m = 0; m < 9; m++) A[m] = 0.0f;
#pragma unroll
    for (int b = 0; b < 4; b++)
        if (b < nb) NODE_BATCH_E1((size_t)boff + (size_t)b * 8);
    for (int b = 4; b < nb; b++) {
        size_t j0 = (size_t)boff + (size_t)b * 8;
        NODE_BATCH_E1(j0);
    }
    const float invn = 1.0f / 16.0f;  // AVG_NEI
    float q = A[0] * invn;
#pragma unroll
    for (int m = 0; m < 9; m++) {
        float a = A[m] * invn;
        q += a * a;
    }
    int type = __builtin_amdgcn_readfirstlane(atom_types[node]);
    float h1n = g_T1[type * 64 + lane];
    float hscn = g_T2[type * 64 + lane];
#pragma unroll
    for (int k = 0; k < 64; k++) {
        float qk = __shfl(q, k, 64);
        h1n += qk * g_M12[k * 128 + lane];
        hscn += qk * g_M12[k * 128 + 64 + lane];
    }
    g_h1b[node * 64 + lane] = h1n;
    g_hscb[node * 64 + lane] = hscn;
    float v = q * g_wp0ro[lane];
#pragma unroll
    for (int off = 32; off > 0; off >>= 1) v += __shfl_down(v, off, 64);
    if (lane == 0) g_nodeE[0][node] = v + g_t0[type];
}

// Layer-1: node_e = q.(Wp1@wro1) + hscb.wro1 — no matvec, no h store.
// Self-cleans g_deg/g_cursor (2 plain stores; NO fence, NO counter — r11).
__global__ __launch_bounds__(256) void k_node1(const float* __restrict__ wro) {
    int t = threadIdx.x;
    int node = blockIdx.x * 4 + (t >> 6);
    int lane = t & 63;
    int boff = __builtin_amdgcn_readfirstlane(g_offs[node]);
    int nb = (__builtin_amdgcn_readfirstlane(g_deg[node]) + 7) >> 3;
    const float* __restrict__ hsrc = g_h1b;
    float A[9];
#pragma unroll
    for (int m = 0; m < 9; m++) A[m] = 0.0f;
#pragma unroll
    for (int b = 0; b < 4; b++)
        if (b < nb) NODE_BATCH((size_t)boff + (size_t)b * 8);
    for (int b = 4; b < nb; b++) {
        size_t j0 = (size_t)boff + (size_t)b * 8;
        NODE_BATCH(j0);
    }
    const float invn = 1.0f / 16.0f;  // AVG_NEI
    float q = A[0] * invn;
#pragma unroll
    for (int m = 0; m < 9; m++) {
        float a = A[m] * invn;
        q += a * a;
    }
    float v = q * g_wpro[lane] + g_hscb[node * 64 + lane] * wro[lane];
#pragma unroll
    for (int off = 32; off > 0; off >>= 1) v += __shfl_down(v, off, 64);
    if (lane == 0) {
        g_nodeE[1][node] = v;
        g_deg[node] = 0;      // self-clean for next iteration's k_init
        g_cursor[node] = 0;
    }
}

// One wave per graph; batch is sorted -> binary-search the node range,
// coalesced reduce, single plain store. Zero atomics (r8/r9: atomics on the
// output buffer cost +66us — never atomic into d_out).
__global__ __launch_bounds__(64) void k_energy(const int* __restrict__ batch,
                                               float* __restrict__ out) {
    int g = blockIdx.x;
    int lane = threadIdx.x;
    int a = 0, b = Nn;
    while (a < b) { int m = (a + b) >> 1; if (batch[m] < g) a = m + 1; else b = m; }
    int st = a;
    b = Nn;
    while (a < b) { int m = (a + b) >> 1; if (batch[m] < g + 1) a = m + 1; else b = m; }
    int en = a;
    float s = 0.0f;
    for (int i = st + lane; i < en; i += 64) s += g_nodeE[0][i] + g_nodeE[1][i];
#pragma unroll
    for (int off = 32; off > 0; off >>= 1) s += __shfl_down(s, off, 64);
    if (lane == 0) out[g] = s;
}

static bool g_first_done = false;

extern "C" void kernel_launch(void* const* d_in, const int* in_sizes, int n_in,
                              void* d_out, int out_size, void* d_ws, size_t ws_size,
                              hipStream_t stream) {
    const float* pos     = (const float*)d_in[0];
    const float* W_embed = (const float*)d_in[1];
    const float* W_r1    = (const float*)d_in[2];
    const float* b_r1    = (const float*)d_in[3];
    const float* W_r2    = (const float*)d_in[4];
    const float* W_up    = (const float*)d_in[5];
    const float* W_sc    = (const float*)d_in[6];
    const float* W_prod  = (const float*)d_in[7];
    const float* w_ro    = (const float*)d_in[8];
    const int* atom_types = (const int*)d_in[9];
    const int* eidx       = (const int*)d_in[10];
    const int* batch      = (const int*)d_in[11];
    float* out = (float*)d_out;

    if (!g_first_done) {
        k_first<<<EDGEBLK, 256, 0, stream>>>(out, out_size);
        g_first_done = true;
    }
    k_init<<<17 + DEGBLK, 256, 0, stream>>>(W_r1, W_embed, W_up, W_sc, W_prod,
                                            w_ro, eidx);
    k_scan<<<1, 1024, 0, stream>>>();
    k_fill<<<DEGBLK, 256, 0, stream>>>(eidx);
    k_edge<<<EDGEBLK, 256, 0, stream>>>(pos, b_r1, W_r2, atom_types);
    k_node0<<<Nn / 4, 256, 0, stream>>>(atom_types);
    k_node1<<<Nn / 4, 256, 0, stream>>>(w_ro + 64);
    k_energy<<<Gg, 64, 0, stream>>>(batch, out);
}